// Round 2
// baseline (208.279 us; speedup 1.0000x reference)
//
#include <hip/hip_runtime.h>
#include <hip/hip_bf16.h>
#include <cmath>

// Problem constants: B=64, T=128, F=188, H=16
#define NROWS   8192            // B*T
#define FDIM    188
#define HDIM    16
#define NCONT   177
#define NCAT    11
#define XSTRIDE 3008            // F*H
#define CHUNK   8               // rows per thread
#define NB      (NROWS / CHUNK) // 1024 row-blocks

// Task layout (one thread per task, no grid-stride):
//   t in [0, NCONT*NB)            : continuous, t = nb*NCONT + cf
//   t in [NCONT*NB, (NCONT+NCAT)*NB): categorical, tt = nb*NCAT + f
// NCONT*NB = 181248 is a multiple of 64 -> no wave mixes the two paths.

__global__ __launch_bounds__(256)
void tab_dec_kernel(const float* __restrict__ x,
                    const float* __restrict__ W2a, const float* __restrict__ b2a,
                    const float* __restrict__ W3,  const float* __restrict__ b3,
                    const float* __restrict__ W4,  const float* __restrict__ b4,
                    const float* __restrict__ W6,  const float* __restrict__ b6,
                    const float* __restrict__ W7,  const float* __restrict__ b7,
                    const float* __restrict__ Wc,  const float* __restrict__ bc,
                    const float* __restrict__ eps,
                    float* __restrict__ out)
{
    const int t  = blockIdx.x * blockDim.x + threadIdx.x;
    const int TC = NCONT * NB;

    if (t < TC) {
        // ---------------- continuous head ----------------
        const int nb = t / NCONT;
        const int cf = t - nb * NCONT;

        // Cache this feature's 32 weights in VGPRs (Wc is 22.7 KB total ->
        // L1/L2-resident; loaded once per thread, amortized over CHUNK rows).
        float w[32];
        const float4* wp = reinterpret_cast<const float4*>(Wc + cf * 32);
        #pragma unroll
        for (int k = 0; k < 8; ++k) {
            float4 v = wp[k];
            w[4*k+0] = v.x; w[4*k+1] = v.y; w[4*k+2] = v.z; w[4*k+3] = v.w;
        }
        const float b0 = bc[cf * 2 + 0];
        const float b1 = bc[cf * 2 + 1];

        const int n0 = nb * CHUNK;
        const float* xbase = x + (size_t)n0 * XSTRIDE + (size_t)(NCAT + cf) * HDIM;

        #pragma unroll 2
        for (int j = 0; j < CHUNK; ++j) {
            const float4* xq = reinterpret_cast<const float4*>(xbase + (size_t)j * XSTRIDE);
            float4 a0 = xq[0], a1 = xq[1], a2 = xq[2], a3 = xq[3];
            float xv[16] = { a0.x, a0.y, a0.z, a0.w,
                             a1.x, a1.y, a1.z, a1.w,
                             a2.x, a2.y, a2.z, a2.w,
                             a3.x, a3.y, a3.z, a3.w };
            float m = b0, s = b1;
            #pragma unroll
            for (int d = 0; d < 16; ++d) {
                m = fmaf(xv[d], w[2*d],     m);
                s = fmaf(xv[d], w[2*d + 1], s);
            }
            // fast tanh: 1 - 2/(e^{2x}+1), clamp keeps exp finite (err <4e-9 at |x|=10)
            float mc   = fminf(fmaxf(m, -10.0f), 10.0f);
            float mean = 1.0f - 2.0f / (__expf(2.0f * mc) + 1.0f);
            float stdv = 1.0f / (1.0f + __expf(-s));
            const int n = n0 + j;
            out[(size_t)n * FDIM + NCAT + cf] =
                fmaf(stdv, eps[(size_t)n * NCONT + cf], mean);
        }
    } else if (t < TC + NCAT * NB) {
        // ---------------- categorical head ----------------
        const int tt = t - TC;
        const int nb = tt / NCAT;
        const int f  = tt - nb * NCAT;

        const float *W, *bb;
        int odim;
        if (f < 4)      { W = W2a + f * HDIM * 2;      bb = b2a + f * 2; odim = 2; }
        else if (f < 6) { W = W3 + (f - 4) * HDIM * 3; bb = b3 + (f - 4) * 3; odim = 3; }
        else if (f < 7) { W = W4;                      bb = b4;          odim = 4; }
        else if (f < 8) { W = W6;                      bb = b6;          odim = 6; }
        else            { W = W7 + (f - 8) * HDIM * 7; bb = b7 + (f - 8) * 7; odim = 7; }

        const int n0 = nb * CHUNK;
        for (int j = 0; j < CHUNK; ++j) {
            const int n = n0 + j;
            const float4* xq = reinterpret_cast<const float4*>(
                x + (size_t)n * XSTRIDE + (size_t)f * HDIM);
            float4 a0 = xq[0], a1 = xq[1], a2 = xq[2], a3 = xq[3];
            float xv[16] = { a0.x, a0.y, a0.z, a0.w,
                             a1.x, a1.y, a1.z, a1.w,
                             a2.x, a2.y, a2.z, a2.w,
                             a3.x, a3.y, a3.z, a3.w };
            float best = -1e30f;
            int   bi   = 0;
            for (int o = 0; o < odim; ++o) {
                float acc = bb[o];              // weights L1-resident (27 KB total)
                #pragma unroll
                for (int d = 0; d < 16; ++d) acc = fmaf(xv[d], W[d * odim + o], acc);
                if (acc > best) { best = acc; bi = o; }   // strict > == first-max (jnp.argmax)
            }
            out[(size_t)n * FDIM + f] = (float)bi;
        }
    }
}

extern "C" void kernel_launch(void* const* d_in, const int* in_sizes, int n_in,
                              void* d_out, int out_size, void* d_ws, size_t ws_size,
                              hipStream_t stream) {
    const float* x   = (const float*)d_in[0];
    const float* W2a = (const float*)d_in[1];
    const float* b2a = (const float*)d_in[2];
    const float* W3  = (const float*)d_in[3];
    const float* b3  = (const float*)d_in[4];
    const float* W4  = (const float*)d_in[5];
    const float* b4  = (const float*)d_in[6];
    const float* W6  = (const float*)d_in[7];
    const float* b6  = (const float*)d_in[8];
    const float* W7  = (const float*)d_in[9];
    const float* b7  = (const float*)d_in[10];
    const float* Wc  = (const float*)d_in[11];
    const float* bc  = (const float*)d_in[12];
    const float* eps = (const float*)d_in[13];
    float* out = (float*)d_out;

    // (NCONT+NCAT)*NB = 188*1024 = 192512 threads = 752 blocks of 256.
    const int total_threads = (NCONT + NCAT) * NB;
    dim3 grid((total_threads + 255) / 256), block(256);
    hipLaunchKernelGGL(tab_dec_kernel, grid, block, 0, stream,
                       x, W2a, b2a, W3, b3, W4, b4, W6, b6, W7, b7, Wc, bc, eps, out);
}

// Round 3
// 190.417 us; speedup vs baseline: 1.0938x; 1.0938x over previous
//
#include <hip/hip_runtime.h>
#include <hip/hip_bf16.h>
#include <cmath>

// Problem constants: B=64, T=128, F=188, H=16
#define NROWS   8192            // B*T
#define FDIM    188
#define HDIM    16
#define NCONT   177
#define NCAT    11
#define XSTRIDE 3008            // F*H

// ---------------- continuous heads: one thread per (row, cont-feature) ----------------
// t = n*NCONT + cf. Consecutive lanes -> consecutive cf -> x/eps/out all coalesced.
// Weights (22.7 KB) are L1-resident; 8 named float4 loads keep them in VGPRs and
// give ~13 independent vmem ops in flight per thread.
__global__ __launch_bounds__(256)
void tab_cont_kernel(const float* __restrict__ x,
                     const float* __restrict__ Wc, const float* __restrict__ bc,
                     const float* __restrict__ eps,
                     float* __restrict__ out)
{
    const int t = blockIdx.x * blockDim.x + threadIdx.x;   // < NROWS*NCONT exactly
    const int n  = t / NCONT;
    const int cf = t - n * NCONT;

    const float4* wp = reinterpret_cast<const float4*>(Wc + cf * 32);
    float4 w0 = wp[0], w1 = wp[1], w2 = wp[2], w3 = wp[3];
    float4 w4 = wp[4], w5 = wp[5], w6 = wp[6], w7 = wp[7];

    const float2 bb = reinterpret_cast<const float2*>(bc)[cf];
    const float  ev = eps[(size_t)n * NCONT + cf];

    const float4* xq = reinterpret_cast<const float4*>(
        x + (size_t)n * XSTRIDE + (size_t)(NCAT + cf) * HDIM);
    float4 a0 = xq[0], a1 = xq[1], a2 = xq[2], a3 = xq[3];

    // interleaved weights: w[2d] -> mean, w[2d+1] -> std-logit
    float m = bb.x, s = bb.y;
    m = fmaf(a0.x, w0.x, m); s = fmaf(a0.x, w0.y, s);
    m = fmaf(a0.y, w0.z, m); s = fmaf(a0.y, w0.w, s);
    m = fmaf(a0.z, w1.x, m); s = fmaf(a0.z, w1.y, s);
    m = fmaf(a0.w, w1.z, m); s = fmaf(a0.w, w1.w, s);
    m = fmaf(a1.x, w2.x, m); s = fmaf(a1.x, w2.y, s);
    m = fmaf(a1.y, w2.z, m); s = fmaf(a1.y, w2.w, s);
    m = fmaf(a1.z, w3.x, m); s = fmaf(a1.z, w3.y, s);
    m = fmaf(a1.w, w3.z, m); s = fmaf(a1.w, w3.w, s);
    m = fmaf(a2.x, w4.x, m); s = fmaf(a2.x, w4.y, s);
    m = fmaf(a2.y, w4.z, m); s = fmaf(a2.y, w4.w, s);
    m = fmaf(a2.z, w5.x, m); s = fmaf(a2.z, w5.y, s);
    m = fmaf(a2.w, w5.z, m); s = fmaf(a2.w, w5.w, s);
    m = fmaf(a3.x, w6.x, m); s = fmaf(a3.x, w6.y, s);
    m = fmaf(a3.y, w6.z, m); s = fmaf(a3.y, w6.w, s);
    m = fmaf(a3.z, w7.x, m); s = fmaf(a3.z, w7.y, s);
    m = fmaf(a3.w, w7.z, m); s = fmaf(a3.w, w7.w, s);

    // fast tanh: 1 - 2/(e^{2x}+1); clamp keeps __expf in range (err < 1e-8 at |x|=10)
    float mc   = fminf(fmaxf(m, -10.0f), 10.0f);
    float mean = 1.0f - 2.0f / (__expf(2.0f * mc) + 1.0f);
    float stdv = 1.0f / (1.0f + __expf(-s));

    out[(size_t)n * FDIM + NCAT + cf] = fmaf(stdv, ev, mean);
}

// ---------------- categorical heads: one thread per (row, cat-feature) ----------------
// t = n*NCAT + f. Only 6% of elements; weights L1-resident.
__global__ __launch_bounds__(256)
void tab_cat_kernel(const float* __restrict__ x,
                    const float* __restrict__ W2a, const float* __restrict__ b2a,
                    const float* __restrict__ W3,  const float* __restrict__ b3,
                    const float* __restrict__ W4,  const float* __restrict__ b4,
                    const float* __restrict__ W6,  const float* __restrict__ b6,
                    const float* __restrict__ W7,  const float* __restrict__ b7,
                    float* __restrict__ out)
{
    const int t = blockIdx.x * blockDim.x + threadIdx.x;
    if (t >= NROWS * NCAT) return;
    const int n = t / NCAT;
    const int f = t - n * NCAT;

    const float4* xq = reinterpret_cast<const float4*>(
        x + (size_t)n * XSTRIDE + (size_t)f * HDIM);
    float4 a0 = xq[0], a1 = xq[1], a2 = xq[2], a3 = xq[3];
    float xv[16] = { a0.x, a0.y, a0.z, a0.w,
                     a1.x, a1.y, a1.z, a1.w,
                     a2.x, a2.y, a2.z, a2.w,
                     a3.x, a3.y, a3.z, a3.w };

    const float *W, *bb;
    int odim;
    if (f < 4)      { W = W2a + f * HDIM * 2;      bb = b2a + f * 2;      odim = 2; }
    else if (f < 6) { W = W3 + (f - 4) * HDIM * 3; bb = b3 + (f - 4) * 3; odim = 3; }
    else if (f < 7) { W = W4;                      bb = b4;               odim = 4; }
    else if (f < 8) { W = W6;                      bb = b6;               odim = 6; }
    else            { W = W7 + (f - 8) * HDIM * 7; bb = b7 + (f - 8) * 7; odim = 7; }

    float best = -1e30f;
    int   bi   = 0;
    for (int o = 0; o < odim; ++o) {
        float acc = bb[o];
        #pragma unroll
        for (int d = 0; d < 16; ++d) acc = fmaf(xv[d], W[d * odim + o], acc);
        if (acc > best) { best = acc; bi = o; }     // strict > == first-max (jnp.argmax)
    }
    out[(size_t)n * FDIM + f] = (float)bi;
}

extern "C" void kernel_launch(void* const* d_in, const int* in_sizes, int n_in,
                              void* d_out, int out_size, void* d_ws, size_t ws_size,
                              hipStream_t stream) {
    const float* x   = (const float*)d_in[0];
    const float* W2a = (const float*)d_in[1];
    const float* b2a = (const float*)d_in[2];
    const float* W3  = (const float*)d_in[3];
    const float* b3  = (const float*)d_in[4];
    const float* W4  = (const float*)d_in[5];
    const float* b4  = (const float*)d_in[6];
    const float* W6  = (const float*)d_in[7];
    const float* b6  = (const float*)d_in[8];
    const float* W7  = (const float*)d_in[9];
    const float* b7  = (const float*)d_in[10];
    const float* Wc  = (const float*)d_in[11];
    const float* bc  = (const float*)d_in[12];
    const float* eps = (const float*)d_in[13];
    float* out = (float*)d_out;

    // Continuous: 8192*177 = 1,449,984 threads = 5664 blocks x 256 (exact).
    hipLaunchKernelGGL(tab_cont_kernel, dim3(NROWS * NCONT / 256), dim3(256), 0, stream,
                       x, Wc, bc, eps, out);
    // Categorical: 8192*11 = 90,112 threads = 352 blocks x 256 (exact).
    hipLaunchKernelGGL(tab_cat_kernel, dim3(NROWS * NCAT / 256), dim3(256), 0, stream,
                       x, W2a, b2a, W3, b3, W4, b4, W6, b6, W7, b7, out);
}

// Round 4
// 187.156 us; speedup vs baseline: 1.1129x; 1.0174x over previous
//
#include <hip/hip_runtime.h>
#include <hip/hip_bf16.h>
#include <cmath>

// Problem constants: B=64, T=128, F=188, H=16
#define NROWS   8192            // B*T
#define FDIM    188
#define HDIM    16
#define NCONT   177
#define NCAT    11
#define XSTRIDE 3008            // F*H

#define CONT_THREADS (NROWS * NCONT)          // 1,449,984 = 5664 * 256 exactly
#define CONT_BLOCKS  (CONT_THREADS / 256)     // 5664
#define CAT_THREADS  (NROWS * NCAT)           // 90,112 = 352 * 256 exactly
#define CAT_BLOCKS   (CAT_THREADS / 256)      // 352

// Fused kernel. Blocks [0,5664): continuous heads, one thread per (row, cont-feature),
// t = n*177+cf (x/eps/out all lane-consecutive -> coalesced). Blocks [5664,6016): categorical.
// Split is block-aligned -> zero divergence, block-uniform __syncthreads.
//
// Weight access: R3 loaded Wc per-thread from L1 with 128B lane stride = 512 L1
// transactions/wave (the bottleneck). Here Wc is staged once per block into LDS as
// 8 float4 "quad planes" sW[k*177+cf]; the per-element fetch is 8x ds_read_b128 from
// ONE vaddr (cf*16) with immediate offsets k*2832 -> ~96 cyc/wave on the LDS pipe,
// overlapping the TA pipe's ~132 txns for x/eps/out.

__global__ __launch_bounds__(256)
void tab_fused_kernel(const float* __restrict__ x,
                      const float* __restrict__ W2a, const float* __restrict__ b2a,
                      const float* __restrict__ W3,  const float* __restrict__ b3,
                      const float* __restrict__ W4,  const float* __restrict__ b4,
                      const float* __restrict__ W6,  const float* __restrict__ b6,
                      const float* __restrict__ W7,  const float* __restrict__ b7,
                      const float* __restrict__ Wc,  const float* __restrict__ bc,
                      const float* __restrict__ eps,
                      float* __restrict__ out)
{
    __shared__ float4 sW[8 * NCONT];   // sW[k*177+cf] = Wc[cf][4k..4k+3]  (22656 B)
    __shared__ float2 sB[NCONT];       // bias (mean, std-logit) per cf     (1416 B)

    const int tid = threadIdx.x;

    if (blockIdx.x < CONT_BLOCKS) {
        // ---- stage weights (coalesced float4 reads; i == cf*8+k exactly) ----
        const float4* wp4 = reinterpret_cast<const float4*>(Wc);
        for (int i = tid; i < NCONT * 8; i += 256) {
            int cf = i >> 3, k = i & 7;
            sW[k * NCONT + cf] = wp4[i];
        }
        if (tid < NCONT) sB[tid] = reinterpret_cast<const float2*>(bc)[tid];
        __syncthreads();

        const int t  = blockIdx.x * 256 + tid;        // < CONT_THREADS exactly
        const int n  = t / NCONT;
        const int cf = t - n * NCONT;

        // global loads first (long latency), LDS reads after
        const float4* xq = reinterpret_cast<const float4*>(
            x + (size_t)n * XSTRIDE + (size_t)(NCAT + cf) * HDIM);
        float4 a0 = xq[0], a1 = xq[1], a2 = xq[2], a3 = xq[3];
        const float ev = eps[t];                      // eps is [N,177] flat == t

        float4 w0 = sW[0 * NCONT + cf], w1 = sW[1 * NCONT + cf];
        float4 w2 = sW[2 * NCONT + cf], w3 = sW[3 * NCONT + cf];
        float4 w4 = sW[4 * NCONT + cf], w5 = sW[5 * NCONT + cf];
        float4 w6 = sW[6 * NCONT + cf], w7 = sW[7 * NCONT + cf];
        float2 bb = sB[cf];

        // quad k holds (m,s) weights for x-elements 2k, 2k+1
        float m = bb.x, s = bb.y;
        m = fmaf(a0.x, w0.x, m); s = fmaf(a0.x, w0.y, s);
        m = fmaf(a0.y, w0.z, m); s = fmaf(a0.y, w0.w, s);
        m = fmaf(a0.z, w1.x, m); s = fmaf(a0.z, w1.y, s);
        m = fmaf(a0.w, w1.z, m); s = fmaf(a0.w, w1.w, s);
        m = fmaf(a1.x, w2.x, m); s = fmaf(a1.x, w2.y, s);
        m = fmaf(a1.y, w2.z, m); s = fmaf(a1.y, w2.w, s);
        m = fmaf(a1.z, w3.x, m); s = fmaf(a1.z, w3.y, s);
        m = fmaf(a1.w, w3.z, m); s = fmaf(a1.w, w3.w, s);
        m = fmaf(a2.x, w4.x, m); s = fmaf(a2.x, w4.y, s);
        m = fmaf(a2.y, w4.z, m); s = fmaf(a2.y, w4.w, s);
        m = fmaf(a2.z, w5.x, m); s = fmaf(a2.z, w5.y, s);
        m = fmaf(a2.w, w5.z, m); s = fmaf(a2.w, w5.w, s);
        m = fmaf(a3.x, w6.x, m); s = fmaf(a3.x, w6.y, s);
        m = fmaf(a3.y, w6.z, m); s = fmaf(a3.y, w6.w, s);
        m = fmaf(a3.z, w7.x, m); s = fmaf(a3.z, w7.y, s);
        m = fmaf(a3.w, w7.z, m); s = fmaf(a3.w, w7.w, s);

        // fast tanh: 1 - 2/(e^{2x}+1); clamp keeps __expf in range
        float mc   = fminf(fmaxf(m, -10.0f), 10.0f);
        float mean = 1.0f - 2.0f / (__expf(2.0f * mc) + 1.0f);
        float stdv = 1.0f / (1.0f + __expf(-s));

        out[(size_t)n * FDIM + NCAT + cf] = fmaf(stdv, ev, mean);
    } else {
        // ---------------- categorical heads (6% of elements) ----------------
        const int t = (blockIdx.x - CONT_BLOCKS) * 256 + tid;   // < CAT_THREADS
        const int n = t / NCAT;
        const int f = t - n * NCAT;

        const float4* xq = reinterpret_cast<const float4*>(
            x + (size_t)n * XSTRIDE + (size_t)f * HDIM);
        float4 a0 = xq[0], a1 = xq[1], a2 = xq[2], a3 = xq[3];
        float xv[16] = { a0.x, a0.y, a0.z, a0.w,
                         a1.x, a1.y, a1.z, a1.w,
                         a2.x, a2.y, a2.z, a2.w,
                         a3.x, a3.y, a3.z, a3.w };

        const float *W, *bb;
        int odim;
        if (f < 4)      { W = W2a + f * HDIM * 2;      bb = b2a + f * 2;      odim = 2; }
        else if (f < 6) { W = W3 + (f - 4) * HDIM * 3; bb = b3 + (f - 4) * 3; odim = 3; }
        else if (f < 7) { W = W4;                      bb = b4;               odim = 4; }
        else if (f < 8) { W = W6;                      bb = b6;               odim = 6; }
        else            { W = W7 + (f - 8) * HDIM * 7; bb = b7 + (f - 8) * 7; odim = 7; }

        float best = -1e30f;
        int   bi   = 0;
        for (int o = 0; o < odim; ++o) {
            float acc = bb[o];                        // 4.3 KB total -> L1-resident
            #pragma unroll
            for (int d = 0; d < 16; ++d) acc = fmaf(xv[d], W[d * odim + o], acc);
            if (acc > best) { best = acc; bi = o; }   // strict > == first-max (jnp.argmax)
        }
        out[(size_t)n * FDIM + f] = (float)bi;
    }
}

extern "C" void kernel_launch(void* const* d_in, const int* in_sizes, int n_in,
                              void* d_out, int out_size, void* d_ws, size_t ws_size,
                              hipStream_t stream) {
    const float* x   = (const float*)d_in[0];
    const float* W2a = (const float*)d_in[1];
    const float* b2a = (const float*)d_in[2];
    const float* W3  = (const float*)d_in[3];
    const float* b3  = (const float*)d_in[4];
    const float* W4  = (const float*)d_in[5];
    const float* b4  = (const float*)d_in[6];
    const float* W6  = (const float*)d_in[7];
    const float* b6  = (const float*)d_in[8];
    const float* W7  = (const float*)d_in[9];
    const float* b7  = (const float*)d_in[10];
    const float* Wc  = (const float*)d_in[11];
    const float* bc  = (const float*)d_in[12];
    const float* eps = (const float*)d_in[13];
    float* out = (float*)d_out;

    hipLaunchKernelGGL(tab_fused_kernel, dim3(CONT_BLOCKS + CAT_BLOCKS), dim3(256), 0, stream,
                       x, W2a, b2a, W3, b3, W4, b4, W6, b6, W7, b7, Wc, bc, eps, out);
}